// Round 2
// baseline (911.047 us; speedup 1.0000x reference)
//
#include <hip/hip_runtime.h>
#include <stdint.h>

constexpr int H = 1024;
constexpr int M = 3584;
constexpr int E = 8;
constexpr int T = 2048;
constexpr int ROWS = T * 2;           // 4096 expert-token rows
constexpr int ROWS_PAD = ROWS + 128;  // last-tile overhang slack

typedef __bf16 bf16x8 __attribute__((ext_vector_type(8)));
typedef float floatx4 __attribute__((ext_vector_type(4)));

__device__ __forceinline__ unsigned short f2bf(float f) {
    union { float f; unsigned u; } v; v.f = f;
    unsigned u = v.u;
    u += 0x7fffu + ((u >> 16) & 1u);   // round-to-nearest-even
    return (unsigned short)(u >> 16);
}
__device__ __forceinline__ unsigned pk2(float a, float b) {
    return (unsigned)f2bf(a) | ((unsigned)f2bf(b) << 16);
}

// async global->LDS, 16B per lane; LDS dest = lptr + lane*16 (wave-uniform lptr)
#define GLD16(gptr, lptr)                                                                   \
    __builtin_amdgcn_global_load_lds(                                                       \
        (const __attribute__((address_space(1))) unsigned int*)(gptr),                      \
        (__attribute__((address_space(3))) unsigned int*)(lptr), 16, 0, 0)

// ---------------- X fp32 -> bf16 ----------------
__global__ void k_convert_x(const float* __restrict__ x, unsigned short* __restrict__ xb) {
    const int row = blockIdx.x;
    const int c = threadIdx.x;                       // 256 threads * 4 floats = 1024
    float4 v = ((const float4*)(x + (size_t)row * H))[c];
    uint2 p; p.x = pk2(v.x, v.y); p.y = pk2(v.z, v.w);
    ((uint2*)(xb + (size_t)row * H))[c] = p;
}

// ---------------- weight transpose + convert: [e][k][n] fp32 -> [e][n][k] bf16 ----------
// tile: 64 n x 32 k per block (256 threads, 1 thread = 1 output 16B chunk)
__global__ __launch_bounds__(256) void k_prep_w(
    const float* __restrict__ w_gate, const float* __restrict__ w_up,
    const float* __restrict__ w_down, unsigned short* __restrict__ wgT,
    unsigned short* __restrict__ wuT, unsigned short* __restrict__ wdT) {
    const int z = blockIdx.y;          // 0..23 -> (type, expert)
    const int type = z >> 3, e = z & 7;
    const int bx = blockIdx.x;         // 0..1791
    const float* src; unsigned short* dst; int K, N, ntile, ktile;
    if (type == 0)      { src = w_gate + (size_t)e * H * M; dst = wgT + (size_t)e * H * M;
                          K = H; N = M; ntile = bx % 56; ktile = bx / 56; }
    else if (type == 1) { src = w_up   + (size_t)e * H * M; dst = wuT + (size_t)e * H * M;
                          K = H; N = M; ntile = bx % 56; ktile = bx / 56; }
    else                { src = w_down + (size_t)e * M * H; dst = wdT + (size_t)e * M * H;
                          K = M; N = H; ntile = bx % 16; ktile = bx / 16; }
    const int t = threadIdx.x;
    const int n = ntile * 64 + (t >> 2);
    const int k = ktile * 32 + (t & 3) * 8;
    const float* sp = src + (size_t)k * N + n;
    float v[8];
    #pragma unroll
    for (int j = 0; j < 8; ++j) v[j] = sp[(size_t)j * N];   // wave-coalesced per j
    uint4 o;
    o.x = pk2(v[0], v[1]); o.y = pk2(v[2], v[3]); o.z = pk2(v[4], v[5]); o.w = pk2(v[6], v[7]);
    *(uint4*)(dst + (size_t)n * K + k) = o;
}

// ---------------- router: logits, top-2, weights ----------------
__global__ void k_router(const float* __restrict__ x, const float* __restrict__ gw,
                         float* __restrict__ logits, float* __restrict__ tok_w,
                         int* __restrict__ tok_e, int* __restrict__ counts) {
    const int t = blockIdx.x;
    const int lane = threadIdx.x;                    // 64 threads = 1 wave
    float acc[E] = {0.f,0.f,0.f,0.f,0.f,0.f,0.f,0.f};
    for (int i = 0; i < H / 64; ++i) {
        const int h = lane + 64 * i;
        const float xv = x[(size_t)t * H + h];
        const float4 g0 = ((const float4*)(gw + h * E))[0];
        const float4 g1 = ((const float4*)(gw + h * E))[1];
        acc[0] += xv * g0.x; acc[1] += xv * g0.y; acc[2] += xv * g0.z; acc[3] += xv * g0.w;
        acc[4] += xv * g1.x; acc[5] += xv * g1.y; acc[6] += xv * g1.z; acc[7] += xv * g1.w;
    }
    #pragma unroll
    for (int j = 0; j < E; ++j) {
        #pragma unroll
        for (int off = 32; off > 0; off >>= 1) acc[j] += __shfl_xor(acc[j], off);
    }
    if (lane == 0) {
        float mx = acc[0];
        #pragma unroll
        for (int j = 1; j < E; ++j) mx = fmaxf(mx, acc[j]);
        float p[E];
        #pragma unroll
        for (int j = 0; j < E; ++j) p[j] = __expf(acc[j] - mx);
        int i0 = 0;
        #pragma unroll
        for (int j = 1; j < E; ++j) if (p[j] > p[i0]) i0 = j;   // ties -> lowest idx
        int i1 = (i0 == 0) ? 1 : 0;
        #pragma unroll
        for (int j = 0; j < E; ++j) if (j != i0 && j != i1 && p[j] > p[i1]) i1 = j;
        const float s = p[i0] + p[i1];
        #pragma unroll
        for (int j = 0; j < E; ++j) logits[(size_t)t * E + j] = acc[j];
        tok_w[t * 2 + 0] = p[i0] / s;
        tok_w[t * 2 + 1] = p[i1] / s;
        tok_e[t * 2 + 0] = i0;
        tok_e[t * 2 + 1] = i1;
        atomicAdd(&counts[i0], 1);
        atomicAdd(&counts[i1], 1);
    }
}

// ---------------- offsets + row assignment ----------------
__global__ void k_assign(const int* __restrict__ counts, int* __restrict__ offsets,
                         int* __restrict__ cursors, const int* __restrict__ tok_e,
                         int* __restrict__ row2tok, int* __restrict__ rowslot) {
    __shared__ int soff[E];
    if (threadIdx.x == 0) {
        int o = 0;
        for (int e = 0; e < E; ++e) { soff[e] = o; offsets[e] = o; o += counts[e]; }
    }
    __syncthreads();
    for (int t = threadIdx.x; t < T; t += blockDim.x) {
        #pragma unroll
        for (int j = 0; j < 2; ++j) {
            const int e = tok_e[t * 2 + j];
            const int p = atomicAdd(&cursors[e], 1);
            const int g = soff[e] + p;
            row2tok[g] = t;
            rowslot[t * 2 + j] = g;
        }
    }
}

// ---------------- gate+up fused grouped GEMM + SwiGLU -> hbuf bf16 ----------------
// 128 rows x 64 cols (both gate and up). 2-phase double-buffered LDS:
// iteration t issues global_load_lds for tile t+1 BEFORE ds_read+MFMA of tile t,
// single __syncthreads (vmcnt(0)+lgkmcnt(0) drain) per step.
__global__ __launch_bounds__(256, 3) void k_gemm1(
    const unsigned short* __restrict__ xb, const unsigned short* __restrict__ wgT,
    const unsigned short* __restrict__ wuT, const int* __restrict__ counts,
    const int* __restrict__ offsets, const int* __restrict__ row2tok,
    unsigned short* __restrict__ hbuf) {
    const int e = blockIdx.z;
    const int cnt = counts[e];
    const int rt = blockIdx.x;
    if (rt * 128 >= cnt) return;
    const int nb = blockIdx.y * 64;
    const int off = offsets[e];

    __shared__ unsigned short sA[2][128 * 32];   // 2 x 8 KB
    __shared__ unsigned short sBg[2][64 * 32];   // 2 x 4 KB
    __shared__ unsigned short sBu[2][64 * 32];   // 2 x 4 KB

    const int tid = threadIdx.x;
    const int lane = tid & 63;
    const int wid = tid >> 6;

    const int lr = lane >> 2;          // 0..15
    const int lc = lane & 3;           // 16B chunk
    // A staging: wave wid covers tile rows [wid*32, wid*32+32), 2 issues
    const int r0 = wid * 32 + lr;
    const int r1 = r0 + 16;
    const int swa = lc ^ ((r0 >> 1) & 3);   // ((r+16)>>1)&3 == (r>>1)&3
    const int ar0 = rt * 128 + r0, ar1 = rt * 128 + r1;
    const int g0 = off + ((ar0 < cnt) ? ar0 : cnt - 1);
    const int g1 = off + ((ar1 < cnt) ? ar1 : cnt - 1);
    const unsigned short* pa0 = xb + (size_t)row2tok[g0] * H + swa * 8;
    const unsigned short* pa1 = xb + (size_t)row2tok[g1] * H + swa * 8;
    // B staging: wave wid covers rows [wid*16, wid*16+16), 1 issue per matrix
    const int rbs = wid * 16 + lr;
    const int swb = lc ^ ((rbs >> 1) & 3);
    const size_t wbase = (size_t)e * H * M;
    const unsigned short* pg0 = wgT + wbase + (size_t)(nb + rbs) * H + swb * 8;
    const unsigned short* pu0 = wuT + wbase + (size_t)(nb + rbs) * H + swb * 8;
    const int laOff = wid * 1024;
    const int lbOff = wid * 512;

    // fragment LDS offsets (loop-invariant), reverse the swizzle
    const int q = lane >> 4;
    const int wr = (wid & 1) * 64;     // wave row origin (2x2 wave grid)
    const int wc = (wid >> 1) * 32;    // wave col origin
    int aoff[4], boff[2];
    #pragma unroll
    for (int i = 0; i < 4; ++i) {
        const int ra = wr + i * 16 + (lane & 15);
        aoff[i] = ra * 32 + (q ^ ((ra >> 1) & 3)) * 8;
    }
    #pragma unroll
    for (int i = 0; i < 2; ++i) {
        const int rb = wc + i * 16 + (lane & 15);
        boff[i] = rb * 32 + (q ^ ((rb >> 1) & 3)) * 8;
    }

    floatx4 accg[4][2] = {};
    floatx4 accu[4][2] = {};

    // prologue: stage tile 0 into buffer 0
    GLD16(pa0, &sA[0][laOff]);  GLD16(pa1, &sA[0][laOff + 512]);
    GLD16(pg0, &sBg[0][lbOff]); GLD16(pu0, &sBu[0][lbOff]);
    pa0 += 32; pa1 += 32; pg0 += 32; pu0 += 32;
    __syncthreads();

    constexpr int NT = H / 32;
    int cur = 0;
    for (int t = 0; t < NT; ++t) {
        const int nxt = cur ^ 1;
        if (t + 1 < NT) {   // issue next tile's loads first (latency hides under MFMA)
            GLD16(pa0, &sA[nxt][laOff]);  GLD16(pa1, &sA[nxt][laOff + 512]);
            GLD16(pg0, &sBg[nxt][lbOff]); GLD16(pu0, &sBu[nxt][lbOff]);
            pa0 += 32; pa1 += 32; pg0 += 32; pu0 += 32;
        }
        bf16x8 af[4], bg[2], bu[2];
        #pragma unroll
        for (int i = 0; i < 4; ++i) af[i] = *(const bf16x8*)&sA[cur][aoff[i]];
        #pragma unroll
        for (int i = 0; i < 2; ++i) {
            bg[i] = *(const bf16x8*)&sBg[cur][boff[i]];
            bu[i] = *(const bf16x8*)&sBu[cur][boff[i]];
        }
        #pragma unroll
        for (int ni = 0; ni < 2; ++ni) {
            #pragma unroll
            for (int mi = 0; mi < 4; ++mi) {
                accg[mi][ni] = __builtin_amdgcn_mfma_f32_16x16x32_bf16(af[mi], bg[ni], accg[mi][ni], 0, 0, 0);
                accu[mi][ni] = __builtin_amdgcn_mfma_f32_16x16x32_bf16(af[mi], bu[ni], accu[mi][ni], 0, 0, 0);
            }
        }
        __syncthreads();   // drains vmcnt(0): next buffer ready
        cur = nxt;
    }

    const int rowb = rt * 128;
    const int col0 = nb + wc + (lane & 15);
    #pragma unroll
    for (int mi = 0; mi < 4; ++mi) {
        #pragma unroll
        for (int r = 0; r < 4; ++r) {
            const int row = rowb + wr + mi * 16 + (lane >> 4) * 4 + r;
            if (row < cnt) {
                unsigned short* hp = hbuf + (size_t)(off + row) * M + col0;
                #pragma unroll
                for (int ni = 0; ni < 2; ++ni) {
                    const float g = accg[mi][ni][r];
                    const float u = accu[mi][ni][r];
                    const float sig = 1.f / (1.f + __expf(-g));
                    hp[ni * 16] = f2bf(g * sig * u);
                }
            }
        }
    }
}

// ---------------- down-proj grouped GEMM -> eout fp32 ----------------
// 128 rows x 64 cols, 2-phase double-buffered (same schedule as k_gemm1).
__global__ __launch_bounds__(256, 3) void k_gemm2(
    const unsigned short* __restrict__ hbuf, const unsigned short* __restrict__ wdT,
    const int* __restrict__ counts, const int* __restrict__ offsets,
    float* __restrict__ eout) {
    const int e = blockIdx.z;
    const int cnt = counts[e];
    const int rt = blockIdx.x;
    if (rt * 128 >= cnt) return;
    const int nb = blockIdx.y * 64;   // within H
    const int off = offsets[e];

    __shared__ unsigned short sA[2][128 * 32];   // 2 x 8 KB
    __shared__ unsigned short sB[2][64 * 32];    // 2 x 4 KB

    const int tid = threadIdx.x;
    const int lane = tid & 63;
    const int wid = tid >> 6;

    const int lr = lane >> 2;
    const int lc = lane & 3;
    const int r0 = wid * 32 + lr;
    const int r1 = r0 + 16;
    const int swa = lc ^ ((r0 >> 1) & 3);
    const unsigned short* pa0 = hbuf + (size_t)(off + rt * 128 + r0) * M + swa * 8;
    const unsigned short* pa1 = hbuf + (size_t)(off + rt * 128 + r1) * M + swa * 8;
    const int rbs = wid * 16 + lr;
    const int swb = lc ^ ((rbs >> 1) & 3);
    const size_t wbase = (size_t)e * H * M;
    const unsigned short* pb0 = wdT + wbase + (size_t)(nb + rbs) * M + swb * 8;
    const int laOff = wid * 1024;
    const int lbOff = wid * 512;

    const int q = lane >> 4;
    const int wr = (wid & 1) * 64;
    const int wc = (wid >> 1) * 32;
    int aoff[4], boff[2];
    #pragma unroll
    for (int i = 0; i < 4; ++i) {
        const int ra = wr + i * 16 + (lane & 15);
        aoff[i] = ra * 32 + (q ^ ((ra >> 1) & 3)) * 8;
    }
    #pragma unroll
    for (int i = 0; i < 2; ++i) {
        const int rb = wc + i * 16 + (lane & 15);
        boff[i] = rb * 32 + (q ^ ((rb >> 1) & 3)) * 8;
    }

    floatx4 acc[4][2] = {};

    GLD16(pa0, &sA[0][laOff]); GLD16(pa1, &sA[0][laOff + 512]);
    GLD16(pb0, &sB[0][lbOff]);
    pa0 += 32; pa1 += 32; pb0 += 32;
    __syncthreads();

    constexpr int NT = M / 32;
    int cur = 0;
    for (int t = 0; t < NT; ++t) {
        const int nxt = cur ^ 1;
        if (t + 1 < NT) {
            GLD16(pa0, &sA[nxt][laOff]); GLD16(pa1, &sA[nxt][laOff + 512]);
            GLD16(pb0, &sB[nxt][lbOff]);
            pa0 += 32; pa1 += 32; pb0 += 32;
        }
        bf16x8 af[4], bfr[2];
        #pragma unroll
        for (int i = 0; i < 4; ++i) af[i] = *(const bf16x8*)&sA[cur][aoff[i]];
        #pragma unroll
        for (int i = 0; i < 2; ++i) bfr[i] = *(const bf16x8*)&sB[cur][boff[i]];
        #pragma unroll
        for (int ni = 0; ni < 2; ++ni)
            #pragma unroll
            for (int mi = 0; mi < 4; ++mi)
                acc[mi][ni] = __builtin_amdgcn_mfma_f32_16x16x32_bf16(af[mi], bfr[ni], acc[mi][ni], 0, 0, 0);
        __syncthreads();
        cur = nxt;
    }

    const int rowb = rt * 128;
    const int col0 = nb + wc + (lane & 15);
    #pragma unroll
    for (int mi = 0; mi < 4; ++mi) {
        #pragma unroll
        for (int r = 0; r < 4; ++r) {
            const int row = rowb + wr + mi * 16 + (lane >> 4) * 4 + r;
            if (row < cnt) {
                float* op = eout + (size_t)(off + row) * H + col0;
                #pragma unroll
                for (int ni = 0; ni < 2; ++ni) op[ni * 16] = acc[mi][ni][r];
            }
        }
    }
}

// ---------------- weighted combine ----------------
__global__ void k_combine(const float* __restrict__ eout, const float* __restrict__ tok_w,
                          const int* __restrict__ rowslot, float* __restrict__ out) {
    const int t = blockIdx.x;
    const int c = threadIdx.x;
    const int s0 = rowslot[t * 2 + 0];
    const int s1 = rowslot[t * 2 + 1];
    const float w0 = tok_w[t * 2 + 0];
    const float w1 = tok_w[t * 2 + 1];
    const float4 a = ((const float4*)(eout + (size_t)s0 * H))[c];
    const float4 b = ((const float4*)(eout + (size_t)s1 * H))[c];
    float4 o;
    o.x = w0 * a.x + w1 * b.x;
    o.y = w0 * a.y + w1 * b.y;
    o.z = w0 * a.z + w1 * b.z;
    o.w = w0 * a.w + w1 * b.w;
    ((float4*)(out + (size_t)t * H))[c] = o;
}

// ---------------- launch ----------------
extern "C" void kernel_launch(void* const* d_in, const int* in_sizes, int n_in,
                              void* d_out, int out_size, void* d_ws, size_t ws_size,
                              hipStream_t stream) {
    const float* x      = (const float*)d_in[0];
    const float* gate_w = (const float*)d_in[1];
    const float* w_gate = (const float*)d_in[2];
    const float* w_up   = (const float*)d_in[3];
    const float* w_down = (const float*)d_in[4];
    float* out    = (float*)d_out;
    float* logits = out + (size_t)T * H;

    char* ws = (char*)d_ws;
    constexpr size_t WG_BYTES   = (size_t)E * H * M * 2;        // 58.7 MB per tensor
    constexpr size_t XB_BYTES   = (size_t)T * H * 2;            // 4 MB
    constexpr size_t HBUF_BYTES = (size_t)ROWS_PAD * M * 2;     // ~30.3 MB
    unsigned short* wgT  = (unsigned short*)ws;
    unsigned short* wuT  = (unsigned short*)(ws + WG_BYTES);
    unsigned short* wdT  = (unsigned short*)(ws + 2 * WG_BYTES);
    unsigned short* xb   = (unsigned short*)(ws + 3 * WG_BYTES);
    unsigned short* hbuf = (unsigned short*)(ws + 3 * WG_BYTES + XB_BYTES);
    char* meta           = ws + 3 * WG_BYTES + XB_BYTES + HBUF_BYTES;
    // eout aliases wgT: wgT is dead after k_gemm1; stream order serializes.
    float* eout   = (float*)wgT;
    int* counts   = (int*)(meta + 0);
    int* cursors  = (int*)(meta + 32);
    int* offsets  = (int*)(meta + 64);
    int* tok_e    = (int*)(meta + 128);
    int* rowslot  = (int*)(meta + 128 + 16384);
    int* row2tok  = (int*)(meta + 128 + 32768);
    float* tok_w  = (float*)(meta + 128 + 32768 + 16896);

    hipMemsetAsync(counts, 0, 64, stream);  // counts + cursors

    k_convert_x<<<T, 256, 0, stream>>>(x, xb);
    k_router<<<T, 64, 0, stream>>>(x, gate_w, logits, tok_w, tok_e, counts);
    k_assign<<<1, 256, 0, stream>>>(counts, offsets, cursors, tok_e, row2tok, rowslot);
    k_prep_w<<<dim3(1792, 24), 256, 0, stream>>>(w_gate, w_up, w_down, wgT, wuT, wdT);
    k_gemm1<<<dim3(T / 128, M / 64, E), 256, 0, stream>>>(xb, wgT, wuT, counts, offsets, row2tok, hbuf);
    k_gemm2<<<dim3(T / 128, H / 64, E), 256, 0, stream>>>(hbuf, wdT, counts, offsets, eout);
    k_combine<<<T, 256, 0, stream>>>(eout, tok_w, rowslot, out);
}

// Round 4
// 875.028 us; speedup vs baseline: 1.0412x; 1.0412x over previous
//
#include <hip/hip_runtime.h>
#include <stdint.h>

constexpr int H = 1024;
constexpr int M = 3584;
constexpr int E = 8;
constexpr int T = 2048;
constexpr int ROWS = T * 2;           // 4096 expert-token rows
constexpr int ROWS_PAD = ROWS + 128;  // last-tile overhang slack

typedef __bf16 bf16x8 __attribute__((ext_vector_type(8)));
typedef float floatx4 __attribute__((ext_vector_type(4)));

__device__ __forceinline__ unsigned short f2bf(float f) {
    union { float f; unsigned u; } v; v.f = f;
    unsigned u = v.u;
    u += 0x7fffu + ((u >> 16) & 1u);   // round-to-nearest-even
    return (unsigned short)(u >> 16);
}
__device__ __forceinline__ unsigned pk2(float a, float b) {
    return (unsigned)f2bf(a) | ((unsigned)f2bf(b) << 16);
}

// async global->LDS, 16B per lane; LDS dest = lptr + lane*16 (wave-uniform lptr)
#define GLD16(gptr, lptr)                                                                   \
    __builtin_amdgcn_global_load_lds(                                                       \
        (const __attribute__((address_space(1))) unsigned int*)(gptr),                      \
        (__attribute__((address_space(3))) unsigned int*)(lptr), 16, 0, 0)

// ---------------- X fp32 -> bf16 ----------------
__global__ void k_convert_x(const float* __restrict__ x, unsigned short* __restrict__ xb) {
    const int row = blockIdx.x;
    const int c = threadIdx.x;                       // 256 threads * 4 floats = 1024
    float4 v = ((const float4*)(x + (size_t)row * H))[c];
    uint2 p; p.x = pk2(v.x, v.y); p.y = pk2(v.z, v.w);
    ((uint2*)(xb + (size_t)row * H))[c] = p;
}

// ---------------- weight transpose + convert: [e][k][n] fp32 -> [e][n][k] bf16 ----------
__global__ __launch_bounds__(256) void k_prep_w(
    const float* __restrict__ w_gate, const float* __restrict__ w_up,
    const float* __restrict__ w_down, unsigned short* __restrict__ wgT,
    unsigned short* __restrict__ wuT, unsigned short* __restrict__ wdT) {
    const int z = blockIdx.y;          // 0..23 -> (type, expert)
    const int type = z >> 3, e = z & 7;
    const int bx = blockIdx.x;         // 0..1791
    const float* src; unsigned short* dst; int K, N, ntile, ktile;
    if (type == 0)      { src = w_gate + (size_t)e * H * M; dst = wgT + (size_t)e * H * M;
                          K = H; N = M; ntile = bx % 56; ktile = bx / 56; }
    else if (type == 1) { src = w_up   + (size_t)e * H * M; dst = wuT + (size_t)e * H * M;
                          K = H; N = M; ntile = bx % 56; ktile = bx / 56; }
    else                { src = w_down + (size_t)e * M * H; dst = wdT + (size_t)e * M * H;
                          K = M; N = H; ntile = bx % 16; ktile = bx / 16; }
    const int t = threadIdx.x;
    const int n = ntile * 64 + (t >> 2);
    const int k = ktile * 32 + (t & 3) * 8;
    const float* sp = src + (size_t)k * N + n;
    float v[8];
    #pragma unroll
    for (int j = 0; j < 8; ++j) v[j] = sp[(size_t)j * N];   // wave-coalesced per j
    uint4 o;
    o.x = pk2(v[0], v[1]); o.y = pk2(v[2], v[3]); o.z = pk2(v[4], v[5]); o.w = pk2(v[6], v[7]);
    *(uint4*)(dst + (size_t)n * K + k) = o;
}

// ---------------- router: logits, top-2, weights ----------------
__global__ void k_router(const float* __restrict__ x, const float* __restrict__ gw,
                         float* __restrict__ logits, float* __restrict__ tok_w,
                         int* __restrict__ tok_e, int* __restrict__ counts) {
    const int t = blockIdx.x;
    const int lane = threadIdx.x;                    // 64 threads = 1 wave
    float acc[E] = {0.f,0.f,0.f,0.f,0.f,0.f,0.f,0.f};
    for (int i = 0; i < H / 64; ++i) {
        const int h = lane + 64 * i;
        const float xv = x[(size_t)t * H + h];
        const float4 g0 = ((const float4*)(gw + h * E))[0];
        const float4 g1 = ((const float4*)(gw + h * E))[1];
        acc[0] += xv * g0.x; acc[1] += xv * g0.y; acc[2] += xv * g0.z; acc[3] += xv * g0.w;
        acc[4] += xv * g1.x; acc[5] += xv * g1.y; acc[6] += xv * g1.z; acc[7] += xv * g1.w;
    }
    #pragma unroll
    for (int j = 0; j < E; ++j) {
        #pragma unroll
        for (int off = 32; off > 0; off >>= 1) acc[j] += __shfl_xor(acc[j], off);
    }
    if (lane == 0) {
        float mx = acc[0];
        #pragma unroll
        for (int j = 1; j < E; ++j) mx = fmaxf(mx, acc[j]);
        float p[E];
        #pragma unroll
        for (int j = 0; j < E; ++j) p[j] = __expf(acc[j] - mx);
        int i0 = 0;
        #pragma unroll
        for (int j = 1; j < E; ++j) if (p[j] > p[i0]) i0 = j;   // ties -> lowest idx
        int i1 = (i0 == 0) ? 1 : 0;
        #pragma unroll
        for (int j = 0; j < E; ++j) if (j != i0 && j != i1 && p[j] > p[i1]) i1 = j;
        const float s = p[i0] + p[i1];
        #pragma unroll
        for (int j = 0; j < E; ++j) logits[(size_t)t * E + j] = acc[j];
        tok_w[t * 2 + 0] = p[i0] / s;
        tok_w[t * 2 + 1] = p[i1] / s;
        tok_e[t * 2 + 0] = i0;
        tok_e[t * 2 + 1] = i1;
        atomicAdd(&counts[i0], 1);
        atomicAdd(&counts[i1], 1);
    }
}

// ---------------- offsets + row assignment ----------------
__global__ void k_assign(const int* __restrict__ counts, int* __restrict__ offsets,
                         int* __restrict__ cursors, const int* __restrict__ tok_e,
                         int* __restrict__ row2tok, int* __restrict__ rowslot) {
    __shared__ int soff[E];
    if (threadIdx.x == 0) {
        int o = 0;
        for (int e = 0; e < E; ++e) { soff[e] = o; offsets[e] = o; o += counts[e]; }
    }
    __syncthreads();
    for (int t = threadIdx.x; t < T; t += blockDim.x) {
        #pragma unroll
        for (int j = 0; j < 2; ++j) {
            const int e = tok_e[t * 2 + j];
            const int p = atomicAdd(&cursors[e], 1);
            const int g = soff[e] + p;
            row2tok[g] = t;
            rowslot[t * 2 + j] = g;
        }
    }
}

// ---------------- gate+up fused grouped GEMM + SwiGLU -> hbuf bf16 ----------------
// 128 rows x 64 cols. 3-deep software pipeline, COUNTED vmcnt (T4): tiles t+1,t+2
// stay in flight across barriers. Barriers are __builtin_amdgcn_s_barrier()
// (proper convergence modeling) paired with asm waitcnt compiler-fences —
// the verified m201-template form.
__global__ __launch_bounds__(256, 3) void k_gemm1(
    const unsigned short* __restrict__ xb, const unsigned short* __restrict__ wgT,
    const unsigned short* __restrict__ wuT, const int* __restrict__ counts,
    const int* __restrict__ offsets, const int* __restrict__ row2tok,
    unsigned short* __restrict__ hbuf) {
    const int e = blockIdx.z;
    const int cnt = counts[e];
    const int rt = blockIdx.x;
    if (rt * 128 >= cnt) return;
    const int nb = blockIdx.y * 64;
    const int off = offsets[e];

    __shared__ unsigned short sA[3][128 * 32];   // 3 x 8 KB
    __shared__ unsigned short sBg[3][64 * 32];   // 3 x 4 KB
    __shared__ unsigned short sBu[3][64 * 32];   // 3 x 4 KB

    const int tid = threadIdx.x;
    const int lane = tid & 63;
    const int wid = tid >> 6;

    const int lr = lane >> 2;          // 0..15
    const int lc = lane & 3;           // 16B chunk
    const int r0 = wid * 32 + lr;
    const int r1 = r0 + 16;
    const int swa = lc ^ ((r0 >> 1) & 3);   // ((r+16)>>1)&3 == (r>>1)&3
    const int ar0 = rt * 128 + r0, ar1 = rt * 128 + r1;
    const int g0 = off + ((ar0 < cnt) ? ar0 : cnt - 1);
    const int g1 = off + ((ar1 < cnt) ? ar1 : cnt - 1);
    const unsigned short* pa0 = xb + (size_t)row2tok[g0] * H + swa * 8;
    const unsigned short* pa1 = xb + (size_t)row2tok[g1] * H + swa * 8;
    const int rbs = wid * 16 + lr;
    const int swb = lc ^ ((rbs >> 1) & 3);
    const size_t wbase = (size_t)e * H * M;
    const unsigned short* pg0 = wgT + wbase + (size_t)(nb + rbs) * H + swb * 8;
    const unsigned short* pu0 = wuT + wbase + (size_t)(nb + rbs) * H + swb * 8;
    const int laOff = wid * 1024;
    const int lbOff = wid * 512;

    // fragment LDS offsets (loop-invariant), reverse the swizzle
    const int q = lane >> 4;
    const int wr = (wid & 1) * 64;     // wave row origin (2x2 wave grid)
    const int wc = (wid >> 1) * 32;    // wave col origin
    int aoff[4], boff[2];
    #pragma unroll
    for (int i = 0; i < 4; ++i) {
        const int ra = wr + i * 16 + (lane & 15);
        aoff[i] = ra * 32 + (q ^ ((ra >> 1) & 3)) * 8;
    }
    #pragma unroll
    for (int i = 0; i < 2; ++i) {
        const int rb = wc + i * 16 + (lane & 15);
        boff[i] = rb * 32 + (q ^ ((rb >> 1) & 3)) * 8;
    }

    floatx4 accg[4][2] = {};
    floatx4 accu[4][2] = {};

#define G1_STAGE(B)                                                       \
    GLD16(pa0, &sA[(B)][laOff]);  GLD16(pa1, &sA[(B)][laOff + 512]);      \
    GLD16(pg0, &sBg[(B)][lbOff]); GLD16(pu0, &sBu[(B)][lbOff]);           \
    pa0 += 32; pa1 += 32; pg0 += 32; pu0 += 32;

// One pipeline step. WAITVM = "s_waitcnt vmcnt(N)" string: own tile-t loads done,
// deeper prefetches stay in flight. After the reader-barrier we refill the
// just-freed buffer (tile t+3 -> buf cur), then MFMA while those loads fly.
#define G1_STEP(WAITVM, CUR, ISS)                                                           \
    {                                                                                       \
        asm volatile(WAITVM ::: "memory");                                                  \
        __builtin_amdgcn_s_barrier();                                                       \
        bf16x8 af[4], bg[2], bu[2];                                                         \
        _Pragma("unroll")                                                                   \
        for (int i = 0; i < 4; ++i) af[i] = *(const bf16x8*)&sA[(CUR)][aoff[i]];            \
        _Pragma("unroll")                                                                   \
        for (int i = 0; i < 2; ++i) {                                                       \
            bg[i] = *(const bf16x8*)&sBg[(CUR)][boff[i]];                                   \
            bu[i] = *(const bf16x8*)&sBu[(CUR)][boff[i]];                                   \
        }                                                                                   \
        asm volatile("s_waitcnt lgkmcnt(0)" ::: "memory");                                  \
        __builtin_amdgcn_s_barrier();                                                       \
        if (ISS) { G1_STAGE(CUR) }                                                          \
        __builtin_amdgcn_s_setprio(1);                                                      \
        _Pragma("unroll")                                                                   \
        for (int ni = 0; ni < 2; ++ni) {                                                    \
            _Pragma("unroll")                                                               \
            for (int mi = 0; mi < 4; ++mi) {                                                \
                accg[mi][ni] = __builtin_amdgcn_mfma_f32_16x16x32_bf16(af[mi], bg[ni], accg[mi][ni], 0, 0, 0); \
                accu[mi][ni] = __builtin_amdgcn_mfma_f32_16x16x32_bf16(af[mi], bu[ni], accu[mi][ni], 0, 0, 0); \
            }                                                                               \
        }                                                                                   \
        __builtin_amdgcn_s_setprio(0);                                                      \
    }

    constexpr int NT = H / 32;   // 32
    // prologue: stage tiles 0,1,2 (12 loads in flight per wave)
    G1_STAGE(0) G1_STAGE(1) G1_STAGE(2)
    int cur = 0;
    for (int t = 0; t < NT - 2; ++t) {
        // tile t+3 goes to buf (t+3)%3 == cur
        G1_STEP("s_waitcnt vmcnt(8)", cur, (t + 3 < NT));
        cur = (cur == 2) ? 0 : cur + 1;
    }
    G1_STEP("s_waitcnt vmcnt(4)", cur, false);
    cur = (cur == 2) ? 0 : cur + 1;
    G1_STEP("s_waitcnt vmcnt(0)", cur, false);

#undef G1_STEP
#undef G1_STAGE

    const int rowb = rt * 128;
    const int col0 = nb + wc + (lane & 15);
    #pragma unroll
    for (int mi = 0; mi < 4; ++mi) {
        #pragma unroll
        for (int r = 0; r < 4; ++r) {
            const int row = rowb + wr + mi * 16 + (lane >> 4) * 4 + r;
            if (row < cnt) {
                unsigned short* hp = hbuf + (size_t)(off + row) * M + col0;
                #pragma unroll
                for (int ni = 0; ni < 2; ++ni) {
                    const float g = accg[mi][ni][r];
                    const float u = accu[mi][ni][r];
                    const float sig = 1.f / (1.f + __expf(-g));
                    hp[ni * 16] = f2bf(g * sig * u);
                }
            }
        }
    }
}

// ---------------- down-proj grouped GEMM -> eout fp32 ----------------
// Same 3-deep counted-vmcnt pipeline; 3 loads per step -> waits 6/3/0.
__global__ __launch_bounds__(256, 4) void k_gemm2(
    const unsigned short* __restrict__ hbuf, const unsigned short* __restrict__ wdT,
    const int* __restrict__ counts, const int* __restrict__ offsets,
    float* __restrict__ eout) {
    const int e = blockIdx.z;
    const int cnt = counts[e];
    const int rt = blockIdx.x;
    if (rt * 128 >= cnt) return;
    const int nb = blockIdx.y * 64;   // within H
    const int off = offsets[e];

    __shared__ unsigned short sA[3][128 * 32];   // 3 x 8 KB
    __shared__ unsigned short sB[3][64 * 32];    // 3 x 4 KB

    const int tid = threadIdx.x;
    const int lane = tid & 63;
    const int wid = tid >> 6;

    const int lr = lane >> 2;
    const int lc = lane & 3;
    const int r0 = wid * 32 + lr;
    const int r1 = r0 + 16;
    const int swa = lc ^ ((r0 >> 1) & 3);
    const unsigned short* pa0 = hbuf + (size_t)(off + rt * 128 + r0) * M + swa * 8;
    const unsigned short* pa1 = hbuf + (size_t)(off + rt * 128 + r1) * M + swa * 8;
    const int rbs = wid * 16 + lr;
    const int swb = lc ^ ((rbs >> 1) & 3);
    const size_t wbase = (size_t)e * H * M;
    const unsigned short* pb0 = wdT + wbase + (size_t)(nb + rbs) * M + swb * 8;
    const int laOff = wid * 1024;
    const int lbOff = wid * 512;

    const int q = lane >> 4;
    const int wr = (wid & 1) * 64;
    const int wc = (wid >> 1) * 32;
    int aoff[4], boff[2];
    #pragma unroll
    for (int i = 0; i < 4; ++i) {
        const int ra = wr + i * 16 + (lane & 15);
        aoff[i] = ra * 32 + (q ^ ((ra >> 1) & 3)) * 8;
    }
    #pragma unroll
    for (int i = 0; i < 2; ++i) {
        const int rb = wc + i * 16 + (lane & 15);
        boff[i] = rb * 32 + (q ^ ((rb >> 1) & 3)) * 8;
    }

    floatx4 acc[4][2] = {};

#define G2_STAGE(B)                                                       \
    GLD16(pa0, &sA[(B)][laOff]); GLD16(pa1, &sA[(B)][laOff + 512]);       \
    GLD16(pb0, &sB[(B)][lbOff]);                                          \
    pa0 += 32; pa1 += 32; pb0 += 32;

#define G2_STEP(WAITVM, CUR, ISS)                                                           \
    {                                                                                       \
        asm volatile(WAITVM ::: "memory");                                                  \
        __builtin_amdgcn_s_barrier();                                                       \
        bf16x8 af[4], bfr[2];                                                               \
        _Pragma("unroll")                                                                   \
        for (int i = 0; i < 4; ++i) af[i] = *(const bf16x8*)&sA[(CUR)][aoff[i]];            \
        _Pragma("unroll")                                                                   \
        for (int i = 0; i < 2; ++i) bfr[i] = *(const bf16x8*)&sB[(CUR)][boff[i]];           \
        asm volatile("s_waitcnt lgkmcnt(0)" ::: "memory");                                  \
        __builtin_amdgcn_s_barrier();                                                       \
        if (ISS) { G2_STAGE(CUR) }                                                          \
        __builtin_amdgcn_s_setprio(1);                                                      \
        _Pragma("unroll")                                                                   \
        for (int ni = 0; ni < 2; ++ni) {                                                    \
            _Pragma("unroll")                                                               \
            for (int mi = 0; mi < 4; ++mi)                                                  \
                acc[mi][ni] = __builtin_amdgcn_mfma_f32_16x16x32_bf16(af[mi], bfr[ni], acc[mi][ni], 0, 0, 0); \
        }                                                                                   \
        __builtin_amdgcn_s_setprio(0);                                                      \
    }

    constexpr int NT = M / 32;   // 112
    G2_STAGE(0) G2_STAGE(1) G2_STAGE(2)
    int cur = 0;
    for (int t = 0; t < NT - 2; ++t) {
        G2_STEP("s_waitcnt vmcnt(6)", cur, (t + 3 < NT));
        cur = (cur == 2) ? 0 : cur + 1;
    }
    G2_STEP("s_waitcnt vmcnt(3)", cur, false);
    cur = (cur == 2) ? 0 : cur + 1;
    G2_STEP("s_waitcnt vmcnt(0)", cur, false);

#undef G2_STEP
#undef G2_STAGE

    const int rowb = rt * 128;
    const int col0 = nb + wc + (lane & 15);
    #pragma unroll
    for (int mi = 0; mi < 4; ++mi) {
        #pragma unroll
        for (int r = 0; r < 4; ++r) {
            const int row = rowb + wr + mi * 16 + (lane >> 4) * 4 + r;
            if (row < cnt) {
                float* op = eout + (size_t)(off + row) * H + col0;
                #pragma unroll
                for (int ni = 0; ni < 2; ++ni) op[ni * 16] = acc[mi][ni][r];
            }
        }
    }
}

// ---------------- weighted combine ----------------
__global__ void k_combine(const float* __restrict__ eout, const float* __restrict__ tok_w,
                          const int* __restrict__ rowslot, float* __restrict__ out) {
    const int t = blockIdx.x;
    const int c = threadIdx.x;
    const int s0 = rowslot[t * 2 + 0];
    const int s1 = rowslot[t * 2 + 1];
    const float w0 = tok_w[t * 2 + 0];
    const float w1 = tok_w[t * 2 + 1];
    const float4 a = ((const float4*)(eout + (size_t)s0 * H))[c];
    const float4 b = ((const float4*)(eout + (size_t)s1 * H))[c];
    float4 o;
    o.x = w0 * a.x + w1 * b.x;
    o.y = w0 * a.y + w1 * b.y;
    o.z = w0 * a.z + w1 * b.z;
    o.w = w0 * a.w + w1 * b.w;
    ((float4*)(out + (size_t)t * H))[c] = o;
}

// ---------------- launch ----------------
extern "C" void kernel_launch(void* const* d_in, const int* in_sizes, int n_in,
                              void* d_out, int out_size, void* d_ws, size_t ws_size,
                              hipStream_t stream) {
    const float* x      = (const float*)d_in[0];
    const float* gate_w = (const float*)d_in[1];
    const float* w_gate = (const float*)d_in[2];
    const float* w_up   = (const float*)d_in[3];
    const float* w_down = (const float*)d_in[4];
    float* out    = (float*)d_out;
    float* logits = out + (size_t)T * H;

    char* ws = (char*)d_ws;
    constexpr size_t WG_BYTES   = (size_t)E * H * M * 2;        // 58.7 MB per tensor
    constexpr size_t XB_BYTES   = (size_t)T * H * 2;            // 4 MB
    constexpr size_t HBUF_BYTES = (size_t)ROWS_PAD * M * 2;     // ~30.3 MB
    unsigned short* wgT  = (unsigned short*)ws;
    unsigned short* wuT  = (unsigned short*)(ws + WG_BYTES);
    unsigned short* wdT  = (unsigned short*)(ws + 2 * WG_BYTES);
    unsigned short* xb   = (unsigned short*)(ws + 3 * WG_BYTES);
    unsigned short* hbuf = (unsigned short*)(ws + 3 * WG_BYTES + XB_BYTES);
    char* meta           = ws + 3 * WG_BYTES + XB_BYTES + HBUF_BYTES;
    // eout aliases wgT: wgT is dead after k_gemm1; stream order serializes.
    float* eout   = (float*)wgT;
    int* counts   = (int*)(meta + 0);
    int* cursors  = (int*)(meta + 32);
    int* offsets  = (int*)(meta + 64);
    int* tok_e    = (int*)(meta + 128);
    int* rowslot  = (int*)(meta + 128 + 16384);
    int* row2tok  = (int*)(meta + 128 + 32768);
    float* tok_w  = (float*)(meta + 128 + 32768 + 16896);

    hipMemsetAsync(counts, 0, 64, stream);  // counts + cursors

    k_convert_x<<<T, 256, 0, stream>>>(x, xb);
    k_router<<<T, 64, 0, stream>>>(x, gate_w, logits, tok_w, tok_e, counts);
    k_assign<<<1, 256, 0, stream>>>(counts, offsets, cursors, tok_e, row2tok, rowslot);
    k_prep_w<<<dim3(1792, 24), 256, 0, stream>>>(w_gate, w_up, w_down, wgT, wuT, wdT);
    k_gemm1<<<dim3(T / 128, M / 64, E), 256, 0, stream>>>(xb, wgT, wuT, counts, offsets, row2tok, hbuf);
    k_gemm2<<<dim3(T / 128, H / 64, E), 256, 0, stream>>>(hbuf, wdT, counts, offsets, eout);
    k_combine<<<T, 256, 0, stream>>>(eout, tok_w, rowslot, out);
}